// Round 9
// baseline (266.404 us; speedup 1.0000x reference)
//
#include <hip/hip_runtime.h>
#include <cstdint>
#include <cstddef>

typedef unsigned short u16;
typedef __attribute__((ext_vector_type(8))) short bf16x8;
typedef __attribute__((ext_vector_type(4))) float f32x4;
typedef __attribute__((ext_vector_type(8))) unsigned short u16x8;

#define T_TOK 8192
#define H_DIM 1024
#define F_DIM 4096
#define E_NUM 8
#define CAP (T_TOK / E_NUM)

__device__ __forceinline__ u16 f2bf(float f) {
  union { float f; uint32_t u; } v; v.f = f;
  uint32_t r = v.u + 0x7FFFu + ((v.u >> 16) & 1u);
  return (u16)(r >> 16);
}

__device__ __forceinline__ float gelu_tanh(float x) {
  float z2 = 1.5957691216057308f * (x + 0.044715f * x * x * x);
  float e = __expf(z2);
  return x * (1.0f - 1.0f / (e + 1.0f));
}

__device__ __forceinline__ void async_copy16(const void* gsrc, void* ldst) {
  __builtin_amdgcn_global_load_lds(
      (const __attribute__((address_space(1))) uint32_t*)gsrc,
      (__attribute__((address_space(3))) uint32_t*)ldst, 16, 0, 0);
}

__device__ __forceinline__ void wgbar() {
  asm volatile("" ::: "memory");
  __builtin_amdgcn_s_barrier();
  asm volatile("" ::: "memory");
}

template <int N> __device__ __forceinline__ void vm_wait() {
  static_assert(N == 0 || N == 4, "vm_wait: unsupported N");
  if constexpr (N == 0) asm volatile("s_waitcnt vmcnt(0)" ::: "memory");
  else if constexpr (N == 4) asm volatile("s_waitcnt vmcnt(4)" ::: "memory");
}

// ---- fp32 -> bf16 convert ----
__global__ __launch_bounds__(256) void k_convert(const float* __restrict__ src,
                                                 u16* __restrict__ dst, long n) {
  long i = ((long)blockIdx.x * 256 + threadIdx.x) * 8;
  long stride = (long)gridDim.x * 256 * 8;
  for (; i < n; i += stride) {
    const float4 a = *(const float4*)(src + i);
    const float4 b = *(const float4*)(src + i + 4);
    u16x8 o;
    o[0] = f2bf(a.x); o[1] = f2bf(a.y); o[2] = f2bf(a.z); o[3] = f2bf(a.w);
    o[4] = f2bf(b.x); o[5] = f2bf(b.y); o[6] = f2bf(b.z); o[7] = f2bf(b.w);
    *(u16x8*)(dst + i) = o;
  }
}

// ---- w2 [E][F][H] fp32 -> w2t [E][H][F] bf16 ----
__global__ __launch_bounds__(256) void k_transpose_w2(const float* __restrict__ w2,
                                                      u16* __restrict__ w2t) {
  __shared__ float tile[32][33];
  const int ntH = H_DIM / 32;
  const int ntF = F_DIM / 32;
  int bid = blockIdx.x;
  int e = bid / (ntF * ntH);
  int r = bid % (ntF * ntH);
  int f0 = (r / ntH) * 32;
  int h0 = (r % ntH) * 32;
  const float* src = w2 + (size_t)e * F_DIM * H_DIM;
  u16* dst = w2t + (size_t)e * H_DIM * F_DIM;
  int col = threadIdx.x & 31;
  int row8 = threadIdx.x >> 5;
#pragma unroll
  for (int i = 0; i < 4; i++) {
    int row = row8 + i * 8;
    tile[row][col] = src[(size_t)(f0 + row) * H_DIM + h0 + col];
  }
  __syncthreads();
#pragma unroll
  for (int i = 0; i < 4; i++) {
    int row = row8 + i * 8;
    dst[(size_t)(h0 + row) * F_DIM + f0 + col] = f2bf(tile[col][row]);
  }
}

// ==== 2-blocks/CU GEMM: C = A(128-rows x K) * B^T (B=[N][K]) bf16 K-contig.
// 128x128 tile, BK=64 = 2 kh, 4 waves (2x2), 256 thr, wave C = 64x64,
// 16x16x32 MFMA, 16 MFMA per phase. LDS = 64 KB -> 2 blocks/CU: cross-block
// wave interleave fills MFMA/LDS/barrier stalls (m114/m97 mechanism) that a
// single phase-locked block exposes.
// Pieces: A[4]=[128][32] u16 (8 KB), B[4]=[128][32]; slot = (t&1)*2+kh.
// Phase q (kh): [ds_read 8 frags][stage next pieces][barrier]
//              [MFMA x16, compiler-counted lgkm][q1 only: vmcnt][barrier].
// Stage stream: t q0 -> (t+1,kh1) A+B; t q1 -> (t+2,kh0) A+B. ONE vmcnt per
// K-tile at q1-end: wait<4> leaves newest 4 (t+2,kh0) -> certifies BOTH
// (t+1,kh0) [staged t-1 q1] and (t+1,kh1) [staged t q0], one barrier before
// tile t+1's first read. Prologue stages 12, wait<4> certifies t0 both kh.
// Tail t>=NT-2: wait<0>.
template <int NTN, int NT, bool GELU>
__global__ __launch_bounds__(256, 2) void k_gemm(const u16* __restrict__ Ag,
                                                 const u16* __restrict__ Bg,
                                                 void* __restrict__ Cg) {
  constexpr int K = NT * 64;
  constexpr int FM = 4, FN = 4;       // wave 64x64 -> 4x4 frags
  constexpr int PA = 128 * 32;        // u16 per piece (8 KB)
  constexpr int PB = 128 * 32;
  constexpr int ABOFF = 4 * PA;
  constexpr int JA = 2, JB = 2;       // stage instr/thread per piece
  constexpr int NTOT = NTN * 128;
  constexpr int NTM = 64;             // 8192/128
  constexpr int NWG = NTM * NTN;

  __shared__ __align__(16) u16 lds[ABOFF + 4 * PB];

  const int tid = threadIdx.x;
  const int lane = tid & 63;
  const int wave = tid >> 6;          // 0..3
  const int wm = wave >> 1;           // 0..1
  const int wn = wave & 1;            // 0..1

  // bijective XCD swizzle (NWG%8==0) + 4x4 supertile decode
  const int wg = ((int)blockIdx.x & 7) * (NWG / 8) + ((int)blockIdx.x >> 3);
  constexpr int NSN = NTN / 4;
  const int sup = wg >> 4, win = wg & 15;
  const int mt = (sup / NSN) * 4 + (win >> 2);
  const int nt_ = (sup % NSN) * 4 + (win & 3);

  const int e = mt >> 3;  // CAP/128 = 8 m-tiles per expert
  const u16* Ae = Ag + (size_t)mt * 128 * K;
  const u16* Be = Bg + (size_t)e * NTOT * K + (size_t)nt_ * 128 * K;

  // ---- hoisted stage addressing (LDS dest linear; src k-slot pre-swizzled) ----
  const int srow = lane >> 2;
  const int kswz = (((lane & 3) ^ ((lane >> 3) & 3)) << 3);
  const u16* srcA[JA];
  int dstA[JA];
  const u16* srcB[JB];
  int dstB[JB];
#pragma unroll
  for (int j = 0; j < JA; ++j) {
    const int cr = (JA * wave + j) * 16 + srow;   // rows 0..127 over 4 waves x 2
    srcA[j] = Ae + (size_t)cr * K + kswz;
    dstA[j] = (JA * wave + j) * 512;
  }
#pragma unroll
  for (int j = 0; j < JB; ++j) {
    const int cr = (JB * wave + j) * 16 + srow;
    srcB[j] = Be + (size_t)cr * K + kswz;
    dstB[j] = (JB * wave + j) * 512;
  }

  auto stageA = [&](int t, int kh) {
    const int pc = (t & 1) * 2 + kh;
    const int koff = t * 64 + kh * 32;
#pragma unroll
    for (int j = 0; j < JA; ++j)
      async_copy16(srcA[j] + koff, &lds[pc * PA + dstA[j]]);
  };
  auto stageB = [&](int t, int kh) {
    const int pc = (t & 1) * 2 + kh;
    const int koff = t * 64 + kh * 32;
#pragma unroll
    for (int j = 0; j < JB; ++j)
      async_copy16(srcB[j] + koff, &lds[ABOFF + pc * PB + dstB[j]]);
  };

  // ---- hoisted frag-read addressing (zero-conflict layout, r2-verified) ----
  const int frow = lane & 15;
  const int fslot = (((lane >> 4) ^ ((lane >> 1) & 3)) << 3);
  const int aoff = (wm * 64 + frow) * 32 + fslot;   // + frag*512
  const int boff = (wn * 64 + frow) * 32 + fslot;

  f32x4 acc[FM][FN] = {};
  bf16x8 af[FM], bf[FN];   // consumed same phase

  auto rdB = [&](int pc) {
    const u16* pb = &lds[ABOFF + pc * PB + boff];
#pragma unroll
    for (int j = 0; j < FN; ++j) bf[j] = *(const bf16x8*)(pb + j * 512);
  };
  auto rdA = [&](int pc) {
    const u16* pa = &lds[pc * PA + aoff];
#pragma unroll
    for (int i = 0; i < FM; ++i) af[i] = *(const bf16x8*)(pa + i * 512);
  };
  auto mfmaC = [&]() {
    __builtin_amdgcn_s_setprio(1);
#pragma unroll
    for (int i = 0; i < FM; ++i)
#pragma unroll
      for (int j = 0; j < FN; ++j)
        acc[i][j] = __builtin_amdgcn_mfma_f32_16x16x32_bf16(af[i], bf[j],
                                                            acc[i][j], 0, 0, 0);
    __builtin_amdgcn_s_setprio(0);
  };

  // prologue: 12 stage instrs; wait<4> certifies t0 kh0+kh1, leaves t1kh0.
  stageA(0, 0); stageB(0, 0);
  stageA(0, 1); stageB(0, 1);
  stageA(1, 0); stageB(1, 0);
  vm_wait<4>();
  wgbar();

  for (int t = 0; t < NT; ++t) {
    const int p0 = (t & 1) * 2, p1 = p0 + 1;
    // q0: kh0
    rdB(p0); rdA(p0);
    if (t < NT - 1) { stageA(t + 1, 1); stageB(t + 1, 1); }
    wgbar();
    mfmaC();
    wgbar();
    // q1: kh1
    rdB(p1); rdA(p1);
    if (t < NT - 2) { stageA(t + 2, 0); stageB(t + 2, 0); }
    wgbar();
    mfmaC();
    if (t >= NT - 2) vm_wait<0>(); else vm_wait<4>();
    wgbar();
  }

  // epilogue: C/D layout col=lane&15, row=(lane>>4)*4+reg
  const int lr = (lane >> 4) * 4;
  const int lc = lane & 15;
  const size_t Crow0 = (size_t)mt * 128 + wm * 64;
  const int Ccol0 = nt_ * 128 + wn * 64;
#pragma unroll
  for (int fm = 0; fm < FM; ++fm)
#pragma unroll
    for (int fn = 0; fn < FN; ++fn) {
      const int col = Ccol0 + fn * 16 + lc;
#pragma unroll
      for (int r = 0; r < 4; ++r) {
        const size_t row = Crow0 + fm * 16 + lr + r;
        if constexpr (GELU) {
          ((u16*)Cg)[row * NTOT + col] = f2bf(gelu_tanh(acc[fm][fn][r]));
        } else {
          ((float*)Cg)[row * NTOT + col] = acc[fm][fn][r];
        }
      }
    }
}

extern "C" void kernel_launch(void* const* d_in, const int* in_sizes, int n_in,
                              void* d_out, int out_size, void* d_ws, size_t ws_size,
                              hipStream_t stream) {
  const float* x = (const float*)d_in[0];
  const float* w1 = (const float*)d_in[1];
  const float* w2 = (const float*)d_in[2];

  u16* ws_x = (u16*)d_ws;                               // [T][H] bf16
  u16* ws_w1 = ws_x + (size_t)T_TOK * H_DIM;            // [E][F][H] bf16
  u16* ws_w2t = ws_w1 + (size_t)E_NUM * F_DIM * H_DIM;  // [E][H][F] bf16
  u16* ws_h = ws_w2t + (size_t)E_NUM * H_DIM * F_DIM;   // [T][F] bf16
  const size_t need =
      ((size_t)T_TOK * H_DIM + 2 * (size_t)E_NUM * F_DIM * H_DIM + (size_t)T_TOK * F_DIM) * 2;
  if (ws_size < need) return;

  k_convert<<<1024, 256, 0, stream>>>(x, ws_x, (long)T_TOK * H_DIM);
  k_convert<<<2048, 256, 0, stream>>>(w1, ws_w1, (long)E_NUM * F_DIM * H_DIM);
  k_transpose_w2<<<E_NUM * (F_DIM / 32) * (H_DIM / 32), 256, 0, stream>>>(w2, ws_w2t);

  // GEMM1: h = gelu(x_e @ w1_e^T) -> [T][F] bf16
  //   tile 128x128, NTN=32, NT=16 -> 2048 blocks, 2 blocks/CU
  k_gemm<32, 16, true><<<2048, 256, 0, stream>>>(ws_x, ws_w1, ws_h);
  // GEMM2: out = h_e @ w2t_e^T -> [T][H] f32
  //   tile 128x128, NTN=8, NT=64 -> 512 blocks, 2 blocks/CU
  k_gemm<8, 64, false><<<512, 256, 0, stream>>>(ws_h, ws_w2t, d_out);
}